// Round 3
// baseline (12268.730 us; speedup 1.0000x reference)
//
#include <hip/hip_runtime.h>
#include <stdint.h>

// GRU: B=128, T=1024, D=512, H=512, C=2. gates [z,r,h], reset_after=True.
// Round 3: contention-free sync. 128 wgs x 384 thr (6 waves). Each wg owns
// [16 b-rows x 32 hidden-cols]x3 gates; W,R fragments in VGPRs (128/lane).
// Inter-wg: monotone per-wg progress words (release store), waiters use
// coherent (L2-bypass) atomic loads; NO acquire fence -> L2 stays warm for x.
// h exchanged fp32 through MALL via 8B agent atomic load/store.

#define NWG   128
#define BT    384
#define Tseq  1024
#define Bdim  128
#define Ddim  512
#define Hdim  512
#define NH3   1536

typedef __attribute__((ext_vector_type(8))) short short8;
typedef __attribute__((ext_vector_type(4))) float f32x4;

union U4S8 { uint4 u; short8 s; };
union PK8 { float f[2]; unsigned long long u; };

__device__ __forceinline__ unsigned short f2bf(float f) {
  unsigned u = __float_as_uint(f);
  unsigned r = (u + 0x7FFFu + ((u >> 16) & 1u)) >> 16;  // RNE
  return (unsigned short)r;
}
__device__ __forceinline__ unsigned pack2(float a, float b) {
  return (unsigned)f2bf(a) | ((unsigned)f2bf(b) << 16);
}
__device__ __forceinline__ float bsig(float x) { return 1.f / (1.f + __expf(-x)); }
__device__ __forceinline__ float btanh(float x) {
  float a = fabsf(x);
  float e = __expf(-2.f * a);
  float t = (1.f - e) / (1.f + e);
  return x < 0.f ? -t : t;
}

// ---- x staging: plain cached float4 loads -> bf16 LDS [16][512], swizzled.
// Swizzle (G4): byte ^= (row&7)<<4 — breaks the 1KB-row-stride bank conflict
// on the 16B readA loads; write pattern stays conflict-free (lanes stride 16B).
__device__ __forceinline__ void stageX(unsigned short* lds, const float* src,
                                       int tid) {
  for (int c = tid; c < 1024; c += BT) {  // 1024 granules of 8 floats
    int row = c >> 6, cb = c & 63;
    const float* p = src + (size_t)row * ((size_t)Tseq * Ddim) + (size_t)cb * 8;
    float4 a = *(const float4*)p;
    float4 b = *(const float4*)(p + 4);
    uint4 v;
    v.x = pack2(a.x, a.y); v.y = pack2(a.z, a.w);
    v.z = pack2(b.x, b.y); v.w = pack2(b.z, b.w);
    int byte = (row << 10) | (((cb << 4) ^ ((row & 7) << 4)));
    *(uint4*)((char*)lds + byte) = v;
  }
}

// ---- h staging: coherent 8B atomic loads (bypass L1/L2 -> MALL) -> bf16 LDS.
__device__ __forceinline__ void stageH(unsigned short* lds, const float* src,
                                       int brow0, int tid) {
  for (int c = tid; c < 4096; c += BT) {  // 4096 pairs (16 rows x 256 pairs)
    int row = c >> 8, cp = c & 255;
    const long long* p =
        (const long long*)(src + (size_t)(brow0 + row) * Hdim + (size_t)cp * 2);
    long long raw = __hip_atomic_load(p, __ATOMIC_RELAXED, __HIP_MEMORY_SCOPE_AGENT);
    PK8 pk; pk.u = (unsigned long long)raw;
    unsigned w = pack2(pk.f[0], pk.f[1]);
    int byte = (row << 10) | (((cp << 2) ^ ((row & 7) << 4)));
    *(unsigned*)((char*)lds + byte) = w;
  }
}

// A-fragment for mfma_f32_16x16x32_bf16: lane l holds A[l&15][(l>>4)*8 + j].
__device__ __forceinline__ short8 readA(const unsigned short* lds, int lane, int kk) {
  int row = lane & 15, kg = lane >> 4;
  int byte = (row << 10) | ((((kk << 6) + (kg << 4)) ^ ((row & 7) << 4)));
  U4S8 t;
  t.u = *(const uint4*)((const char*)lds + byte);
  return t.s;
}

__global__ __launch_bounds__(BT, 2) void gru_persist(
    const float* __restrict__ x, const float* __restrict__ W,
    const float* __restrict__ R, const float* __restrict__ b_i,
    const float* __restrict__ b_r, int* __restrict__ prog,
    float* __restrict__ h0, float* __restrict__ h1) {
  __shared__ alignas(16) unsigned short hA[16 * 512];
  __shared__ alignas(16) unsigned short xA[16 * 512];
  __shared__ float tg[4][512];  // pre_z, pre_r, xh+bi, hp+br  ([16 rows][32 cols])

  const int tid  = threadIdx.x;
  const int lane = tid & 63;
  const int w    = tid >> 6;          // wave 0..5
  const int g    = w >> 1;            // gate 0:z 1:r 2:h
  const int c    = w & 1;             // col-tile within wg
  const int wg   = blockIdx.x;
  const int brow0 = (wg & 7) << 4;    // 8 row-groups of 16
  const int cg    = wg >> 3;          // 16 col-groups of 32 hidden cols
  const int colL  = lane & 15;
  const int kg    = lane >> 4;
  const int gcol  = cg * 32 + c * 16 + colL;       // hidden col [0,512)
  const int gc    = g * Hdim + gcol;               // gate col [0,1536)

  // ---- one-time: B-fragments of W and R into VGPRs ----
  // B-frag: lane l holds M[kk*32 + (l>>4)*8 + j][gc].
  short8 Wf_[16], Rf_[16];
#pragma unroll
  for (int kk = 0; kk < 16; ++kk) {
    short8 wv, rv;
#pragma unroll
    for (int j = 0; j < 8; ++j) {
      int k = kk * 32 + kg * 8 + j;
      wv[j] = (short)f2bf(W[(size_t)k * NH3 + gc]);
      rv[j] = (short)f2bf(R[(size_t)k * NH3 + gc]);
    }
    Wf_[kk] = wv; Rf_[kk] = rv;
  }
  const float bi = b_i[gc];
  const float br = b_r[gc];

  // ---- prologue: xp for t=0 ----
  stageX(xA, x + (size_t)brow0 * (Tseq * Ddim), tid);
  __syncthreads();
  f32x4 aX0 = {0,0,0,0}, aX1 = {0,0,0,0};
#pragma unroll
  for (int kk = 0; kk < 8; ++kk) {
    aX0 = __builtin_amdgcn_mfma_f32_16x16x32_bf16(readA(xA, lane, 2*kk),   Wf_[2*kk],   aX0, 0, 0, 0);
    aX1 = __builtin_amdgcn_mfma_f32_16x16x32_bf16(readA(xA, lane, 2*kk+1), Wf_[2*kk+1], aX1, 0, 0, 0);
  }

  for (int t = 0; t < Tseq; ++t) {
    const float* hin  = (t & 1) ? h1 : h0;
    float*       hout = (t & 1) ? h0 : h1;

    // ---- stage h_t (coherent loads -> bf16 LDS) ----
    stageH(hA, hin, brow0, tid);
    __syncthreads();  // S1

    // ---- hp = h_t @ R (two independent MFMA chains) ----
    f32x4 aH0 = {0,0,0,0}, aH1 = {0,0,0,0};
#pragma unroll
    for (int kk = 0; kk < 8; ++kk) {
      aH0 = __builtin_amdgcn_mfma_f32_16x16x32_bf16(readA(hA, lane, 2*kk),   Rf_[2*kk],   aH0, 0, 0, 0);
      aH1 = __builtin_amdgcn_mfma_f32_16x16x32_bf16(readA(hA, lane, 2*kk+1), Rf_[2*kk+1], aH1, 0, 0, 0);
    }

    // ---- exchange gate tiles (D layout: row=(l>>4)*4+r4, col=l&15) ----
#pragma unroll
    for (int r4 = 0; r4 < 4; ++r4) {
      int row = kg * 4 + r4;
      int e = row * 32 + c * 16 + colL;
      float vx = aX0[r4] + aX1[r4];
      float vh = aH0[r4] + aH1[r4];
      if (g == 0)      tg[0][e] = vx + vh + bi + br;
      else if (g == 1) tg[1][e] = vx + vh + bi + br;
      else {           tg[2][e] = vx + bi;
                       tg[3][e] = vh + br; }
    }
    __syncthreads();  // S2

    // ---- gates + h_new (fp32 carry); write-through agent stores ----
    for (int e2 = tid; e2 < 256; e2 += BT) {  // 256 pairs = 16 rows x 32 cols
      int row = e2 >> 4;
      int col = (e2 & 15) << 1;
      int ez  = row * 32 + col;
      float z0 = bsig(tg[0][ez]),     z1 = bsig(tg[0][ez + 1]);
      float r0 = bsig(tg[1][ez]),     r1 = bsig(tg[1][ez + 1]);
      float hh0 = btanh(tg[2][ez]     + r0 * tg[3][ez]);
      float hh1 = btanh(tg[2][ez + 1] + r1 * tg[3][ez + 1]);
      size_t idx = (size_t)(brow0 + row) * Hdim + cg * 32 + col;
      long long raw = __hip_atomic_load((const long long*)&hin[idx],
                                        __ATOMIC_RELAXED, __HIP_MEMORY_SCOPE_AGENT);
      PK8 po; po.u = (unsigned long long)raw;
      PK8 pk;
      pk.f[0] = z0 * po.f[0] + (1.f - z0) * hh0;
      pk.f[1] = z1 * po.f[1] + (1.f - z1) * hh1;
      __hip_atomic_store((unsigned long long*)&hout[idx], pk.u,
                         __ATOMIC_RELAXED, __HIP_MEMORY_SCOPE_AGENT);
    }
    // each thread drains its own stores to the coherence point, then wg-sync
    __builtin_amdgcn_fence(__ATOMIC_RELEASE, "agent");
    __syncthreads();  // S3: all h stores of this wg are globally visible

    // ---- arrive: monotone progress word (no RMW, no contention) ----
    if (tid == 0)
      __hip_atomic_store(&prog[wg], t + 1, __ATOMIC_RELAXED, __HIP_MEMORY_SCOPE_AGENT);

    // ---- overlap with other wgs' arrivals: xp for t+1 ----
    int tt = (t + 1 < Tseq) ? t + 1 : Tseq - 1;
    stageX(xA, x + (size_t)brow0 * (Tseq * Ddim) + (size_t)tt * Ddim, tid);
    __syncthreads();  // S4
    aX0 = (f32x4){0,0,0,0}; aX1 = (f32x4){0,0,0,0};
#pragma unroll
    for (int kk = 0; kk < 8; ++kk) {
      aX0 = __builtin_amdgcn_mfma_f32_16x16x32_bf16(readA(xA, lane, 2*kk),   Wf_[2*kk],   aX0, 0, 0, 0);
      aX1 = __builtin_amdgcn_mfma_f32_16x16x32_bf16(readA(xA, lane, 2*kk+1), Wf_[2*kk+1], aX1, 0, 0, 0);
    }

    // ---- wait: wave 0 polls all 128 progress words coherently ----
    if (w == 0) {
      const long long* pp = (const long long*)&prog[lane * 2];
      int need = t + 1;
      while (true) {
        long long v = __hip_atomic_load(pp, __ATOMIC_RELAXED, __HIP_MEMORY_SCOPE_AGENT);
        int a = (int)v, b = (int)(v >> 32);
        if (__all(a >= need && b >= need)) break;
      }
    }
    __syncthreads();  // S5: h_{t+1} globally visible; coherent reads next iter
  }
}

__global__ __launch_bounds__(64) void logits_kernel(const float* __restrict__ hbuf,
                                                    const float* __restrict__ Wf,
                                                    const float* __restrict__ bf,
                                                    float* __restrict__ out) {
  int b = blockIdx.x, l = threadIdx.x;
  const float* hr = hbuf + (size_t)b * Hdim;
  float c0 = 0.f, c1 = 0.f;
#pragma unroll
  for (int i = 0; i < 8; ++i) {
    int k = l * 8 + i;
    float h = hr[k];
    c0 += h * Wf[k * 2 + 0];
    c1 += h * Wf[k * 2 + 1];
  }
  for (int off = 32; off > 0; off >>= 1) {
    c0 += __shfl_down(c0, off);
    c1 += __shfl_down(c1, off);
  }
  if (l == 0) {
    out[b * 2 + 0] = c0 + bf[0];
    out[b * 2 + 1] = c1 + bf[1];
  }
}

extern "C" void kernel_launch(void* const* d_in, const int* in_sizes, int n_in,
                              void* d_out, int out_size, void* d_ws, size_t ws_size,
                              hipStream_t stream) {
  (void)in_sizes; (void)n_in; (void)out_size; (void)ws_size;
  const float* x   = (const float*)d_in[0];
  const float* W   = (const float*)d_in[1];
  const float* R   = (const float*)d_in[2];
  const float* b_i = (const float*)d_in[3];
  const float* b_r = (const float*)d_in[4];
  const float* Wf  = (const float*)d_in[5];
  const float* bf  = (const float*)d_in[6];

  char* ws = (char*)d_ws;
  int*   prog = (int*)ws;                              // 128 monotone words
  float* h0   = (float*)(ws + 4096);                   // parity-0 (h_0=0, final h_T)
  float* h1   = (float*)(ws + 4096 + Bdim * Hdim * 4); // parity-1

  // zero prog + h0 (ws is poisoned 0xAA before every timed launch)
  hipMemsetAsync(ws, 0, 4096 + Bdim * Hdim * 4, stream);

  hipLaunchKernelGGL(gru_persist, dim3(NWG), dim3(BT), 0, stream,
                     x, W, R, b_i, b_r, prog, h0, h1);
  // T=1024: final h written at t=1023 (odd) -> parity-0 buffer
  hipLaunchKernelGGL(logits_kernel, dim3(Bdim), dim3(64), 0, stream,
                     h0, Wf, bf, (float*)d_out);
}